// Round 4
// baseline (247.437 us; speedup 1.0000x reference)
//
#include <hip/hip_runtime.h>
#include <hip/hip_bf16.h>
#include <stdint.h>

#define B_ 256
#define H_ 4096
#define K_ 32768   // V*N = 1024*32

typedef __attribute__((ext_vector_type(8))) short bf16x8;
typedef __attribute__((ext_vector_type(4))) float f32x4;

__device__ __forceinline__ unsigned short f2bf(float x) {
    union { float f; unsigned int u; } c; c.f = x;
    unsigned int r = c.u + 0x7FFFu + ((c.u >> 16) & 1u);  // RNE
    return (unsigned short)(r >> 16);
}

__device__ __forceinline__ short bfc(float x) {
    __hip_bfloat16 h = __float2bfloat16(x);
    union { __hip_bfloat16 h; short s; } c; c.h = h;
    return c.s;
}

__device__ __forceinline__ float softplus_f(float x) {
    return fmaxf(x, 0.0f) + log1pf(expf(-fabsf(x)));
}

// ---------------- Kernel A: v fp32->bf16 + vt[b] = dot(v[b,:], b_v) ----------------
__global__ __launch_bounds__(256) void prep_kernel(
    const float* __restrict__ v, const float* __restrict__ bv,
    __hip_bfloat16* __restrict__ vbf, float* __restrict__ vt)
{
    const int b = blockIdx.x;
    const int t = threadIdx.x;
    const float* vr = v + (size_t)b * K_;
    unsigned short* dr = (unsigned short*)(vbf + (size_t)b * K_);
    float acc = 0.f;
    for (int i = t * 8; i < K_; i += 256 * 8) {
        float4 x0 = *(const float4*)(vr + i);
        float4 x1 = *(const float4*)(vr + i + 4);
        float4 b0 = *(const float4*)(bv + i);
        float4 b1 = *(const float4*)(bv + i + 4);
        acc += x0.x*b0.x + x0.y*b0.y + x0.z*b0.z + x0.w*b0.w
             + x1.x*b1.x + x1.y*b1.y + x1.z*b1.z + x1.w*b1.w;
        ushort4 u0, u1;
        u0.x = f2bf(x0.x); u0.y = f2bf(x0.y); u0.z = f2bf(x0.z); u0.w = f2bf(x0.w);
        u1.x = f2bf(x1.x); u1.y = f2bf(x1.y); u1.z = f2bf(x1.z); u1.w = f2bf(x1.w);
        *(ushort4*)(dr + i)     = u0;
        *(ushort4*)(dr + i + 4) = u1;
    }
    __shared__ float sm[256];
    sm[t] = acc;
    __syncthreads();
    for (int s = 128; s > 0; s >>= 1) {
        if (t < s) sm[t] += sm[t + s];
        __syncthreads();
    }
    if (t == 0) vt[b] = sm[0];
}

// ---------------- Kernel B: split-K GEMM, BM=256 BN=64 BK=64 ----------------
// W reg-staged to LDS as BF16 (halves LDS read traffic, moves cvt off the
// consume path): global fp32 -> regs (dist 2) -> cvt -> ds_write into a
// depth-4 8KB ring (XOR-swizzled 16B granules). A (v bf16, XCD-L2-resident)
// direct global->reg, double-buffered. One fused {lgkmcnt(0); s_barrier} per
// K-step; counted vmcnt mid-body drains only Wg(t+1), keeps newer prefetches.
//
// Per-wave vmem FIFO (per body: A(t+1)=4 loads, Wg(t+2)=2 loads, any order):
//   at body t cvt-wait: keep A(t+1)4 + Wg(t+2)2 = 6 -> vmcnt(6) drains
//   Wg(t+1) (and A(t), which is older). Tail: t=NT-2 -> vmcnt(4).
// Ring: write slot (t+1)&3 before bar(t); reads of that slot start after
// bar(t+1); previous reads of the same slot ended before bar(t-2). Safe.

#define GLOAD_W(dst, kt) do {                                                          \
    const float* p_ = wsrcp + (size_t)(kt) * 64;                                       \
    dst[0] = *(const float4*)p_;                                                       \
    dst[1] = *(const float4*)(p_ + 4);                                                 \
    } while (0)

#define CVT_WRITE(WG, slot_) do {                                                      \
    bf16x8 u_;                                                                         \
    u_[0]=bfc(WG[0].x); u_[1]=bfc(WG[0].y); u_[2]=bfc(WG[0].z); u_[3]=bfc(WG[0].w);    \
    u_[4]=bfc(WG[1].x); u_[5]=bfc(WG[1].y); u_[6]=bfc(WG[1].z); u_[7]=bfc(WG[1].w);    \
    *(bf16x8*)&wtile[(slot_)][wslot_off] = u_;                                         \
    } while (0)

#define LOAD_A(dst, kt) do {                                                           \
    _Pragma("unroll")                                                                  \
    for (int m_ = 0; m_ < 2; ++m_)                                                     \
      _Pragma("unroll")                                                                \
      for (int s_ = 0; s_ < 2; ++s_)                                                   \
        dst[m_*2+s_] = *(const bf16x8*)(ap[m_] + (size_t)(kt) * 64 + s_ * 32);         \
    } while (0)

#define COMPUTE(AUSE, T_) do {                                                         \
    const unsigned short* wb_ = &wtile[(T_) & 3][0];                                   \
    _Pragma("unroll")                                                                  \
    for (int s_ = 0; s_ < 2; ++s_) {                                                   \
      bf16x8 bfr[4];                                                                   \
      _Pragma("unroll")                                                                \
      for (int n_ = 0; n_ < 4; ++n_) {                                                 \
        int row_  = n_ * 16 + lr;                                                      \
        int slot_ = s_ * 4 + lg;                                                       \
        bfr[n_] = *(const bf16x8*)&wb_[row_ * 64 + ((slot_ ^ (row_ & 7)) << 3)];       \
      }                                                                                \
      _Pragma("unroll")                                                                \
      for (int m_ = 0; m_ < 2; ++m_)                                                   \
        _Pragma("unroll")                                                              \
        for (int n_ = 0; n_ < 4; ++n_)                                                 \
          acc[m_][n_] = __builtin_amdgcn_mfma_f32_16x16x32_bf16(                       \
              AUSE[m_*2+s_], bfr[n_], acc[m_][n_], 0, 0, 0);                           \
    } } while (0)

#define BODY(T_, AUSE, ALOAD, WGUSE, WGLOAD, ISSA, ISSW, DOCVT, VMSTR) do {            \
    if (ISSA) LOAD_A(ALOAD, (T_) + 1);                                                 \
    if (ISSW) GLOAD_W(WGLOAD, (T_) + 2);                                               \
    if (DOCVT) {                                                                       \
        asm volatile("s_waitcnt " VMSTR ::: "memory");                                 \
        CVT_WRITE(WGUSE, ((T_) + 1) & 3);                                              \
    }                                                                                  \
    asm volatile("s_waitcnt lgkmcnt(0)\n\ts_barrier" ::: "memory");                    \
    COMPUTE(AUSE, T_);                                                                 \
    } while (0)

__global__ __launch_bounds__(512, 4) void gemm_kernel(
    const __hip_bfloat16* __restrict__ vbf,   // [256][32768] bf16
    const float* __restrict__ W,              // [4096][32768] fp32
    float* __restrict__ part,                 // [KS][256][4096] fp32
    int KS, int NT)                           // NT = (K_/KS)/64, even, >= 4
{
    __shared__ __align__(16) unsigned short wtile[4][64 * 64];  // 4 x 8 KB bf16 ring

    const int tid  = threadIdx.x;
    const int wid  = tid >> 6;
    const int lane = tid & 63;
    const int lr   = lane & 15;   // B-frag n / A-frag row-in-16
    const int lg   = lane >> 4;   // k-granule 0..3

    const int bid   = blockIdx.x;
    const int sidx  = bid % KS;   // k-split; == XCD id when KS==8 (v-slice L2 locality)
    const int ht    = bid / KS;
    const int h0    = ht * 64;
    const int kbase = sidx * (NT * 64);

    // W stage addressing: thread stages row rw = tid>>3, 8 floats at col (tid&7)*8.
    // LDS granule (rw, c8) stored at swizzled slot c8 ^ (rw&7).
    const int rw = tid >> 3;
    const int c8 = tid & 7;
    const float* wsrcp = W + (size_t)(h0 + rw) * K_ + kbase + c8 * 8;
    const int wslot_off = rw * 64 + ((c8 ^ (rw & 7)) << 3);   // ushort index

    // A: this wave owns rows wid*32 .. wid*32+31
    const __hip_bfloat16* ap[2];
    #pragma unroll
    for (int m = 0; m < 2; ++m)
        ap[m] = vbf + (size_t)(wid * 32 + m * 16 + lr) * K_ + kbase + lg * 8;

    f32x4 acc[2][4];
    #pragma unroll
    for (int m = 0; m < 2; ++m)
        #pragma unroll
        for (int n = 0; n < 4; ++n)
            acc[m][n] = (f32x4)(0.0f);

    bf16x8 aA[4], aB[4];
    float4 wgA[2], wgB[2];

    // Prologue: A(0), Wg(0)->wgA, Wg(1)->wgB; drain Wg(0) (keep wgB in flight);
    // cvt+write slot 0. Body 0's lgkmcnt(0)+barrier makes it visible.
    LOAD_A(aA, 0);
    GLOAD_W(wgA, 0);
    GLOAD_W(wgB, 1);
    asm volatile("s_waitcnt vmcnt(2)" ::: "memory");
    CVT_WRITE(wgA, 0);
    asm volatile("" ::: "memory");

    // body even: compute aA / consume wgB(t+1) / load aB, wgA(t+2); odd: swap.
    for (int t = 0; t < NT - 2; t += 2) {
        BODY(t,     aA, aB, wgB, wgA, true, true, true, "vmcnt(6)");
        BODY(t + 1, aB, aA, wgA, wgB, true, true, true, "vmcnt(6)");
    }
    BODY(NT - 2, aA, aB, wgB, wgA, true,  false, true,  "vmcnt(4)");
    BODY(NT - 1, aB, aA, wgA, wgB, false, false, false, "vmcnt(0)");

    // Epilogue: C/D layout col=lane&15 (=h), row=(lane>>4)*4+reg (=b)
    float* pout = part + (size_t)sidx * ((size_t)B_ * H_) + h0;
    #pragma unroll
    for (int m = 0; m < 2; ++m)
        #pragma unroll
        for (int n = 0; n < 4; ++n)
            #pragma unroll
            for (int j = 0; j < 4; ++j) {
                int brow = wid * 32 + m * 16 + lg * 4 + j;
                int hcol = n * 16 + lr;
                pout[(size_t)brow * H_ + hcol] = acc[m][n][j];
            }
}

// ---------------- Kernel C: reduce splits + b_h, softplus, sum over H, + vt ----------------
__global__ __launch_bounds__(256) void reduce_kernel(
    const float* __restrict__ part, const float* __restrict__ bh,
    const float* __restrict__ vt, float* __restrict__ out, int KS)
{
    const int b = blockIdx.x;
    const int t = threadIdx.x;
    float sp = 0.f;
    const float* pb = part + (size_t)b * H_;
    for (int h = t * 4; h < H_; h += 256 * 4) {
        float4 l = *(const float4*)(bh + h);
        for (int s = 0; s < KS; ++s) {
            float4 p = *(const float4*)(pb + (size_t)s * B_ * H_ + h);
            l.x += p.x; l.y += p.y; l.z += p.z; l.w += p.w;
        }
        sp += softplus_f(l.x) + softplus_f(l.y) + softplus_f(l.z) + softplus_f(l.w);
    }
    __shared__ float sm[256];
    sm[t] = sp;
    __syncthreads();
    for (int r = 128; r > 0; r >>= 1) {
        if (t < r) sm[t] += sm[t + r];
        __syncthreads();
    }
    if (t == 0) out[b] = sm[0] + vt[b];
}

extern "C" void kernel_launch(void* const* d_in, const int* in_sizes, int n_in,
                              void* d_out, int out_size, void* d_ws, size_t ws_size,
                              hipStream_t stream)
{
    const float* v  = (const float*)d_in[0];
    const float* W  = (const float*)d_in[1];
    const float* bh = (const float*)d_in[2];
    const float* bv = (const float*)d_in[3];
    float* out = (float*)d_out;

    char* ws = (char*)d_ws;
    const size_t vbf_bytes = (size_t)B_ * K_ * sizeof(__hip_bfloat16);  // 16 MB
    __hip_bfloat16* vbf = (__hip_bfloat16*)ws;

    int KS = 8;                                   // shrink if workspace is small
    while (KS > 1 && vbf_bytes + (size_t)KS * B_ * H_ * 4 + 1024 > ws_size) KS >>= 1;

    float* part = (float*)(ws + vbf_bytes);                                  // KS*4 MB
    float* vt   = (float*)(ws + vbf_bytes + (size_t)KS * B_ * H_ * 4);       // 1 KB

    prep_kernel<<<B_, 256, 0, stream>>>(v, bv, vbf, vt);
    const int NT = (K_ / KS) / 64;                // 64 for KS=8 (even, >=4)
    gemm_kernel<<<(H_ / 64) * KS, 512, 0, stream>>>(vbf, W, part, KS, NT);
    reduce_kernel<<<B_, 256, 0, stream>>>(part, bh, vt, out, KS);
}

// Round 5
// 238.595 us; speedup vs baseline: 1.0371x; 1.0371x over previous
//
#include <hip/hip_runtime.h>
#include <hip/hip_bf16.h>
#include <stdint.h>

#define B_ 256
#define H_ 4096
#define K_ 32768   // V*N = 1024*32

typedef __attribute__((ext_vector_type(8))) short bf16x8;
typedef __attribute__((ext_vector_type(4))) float f32x4;

__device__ __forceinline__ unsigned short f2bf(float x) {
    union { float f; unsigned int u; } c; c.f = x;
    unsigned int r = c.u + 0x7FFFu + ((c.u >> 16) & 1u);  // RNE
    return (unsigned short)(r >> 16);
}

__device__ __forceinline__ short bfc(float x) {
    __hip_bfloat16 h = __float2bfloat16(x);
    union { __hip_bfloat16 h; short s; } c; c.h = h;
    return c.s;
}

__device__ __forceinline__ float softplus_f(float x) {
    return fmaxf(x, 0.0f) + log1pf(expf(-fabsf(x)));
}

// ---------------- Kernel A: v fp32->bf16 + vt[b] = dot(v[b,:], b_v) ----------------
__global__ __launch_bounds__(256) void prep_kernel(
    const float* __restrict__ v, const float* __restrict__ bv,
    __hip_bfloat16* __restrict__ vbf, float* __restrict__ vt)
{
    const int b = blockIdx.x;
    const int t = threadIdx.x;
    const float* vr = v + (size_t)b * K_;
    unsigned short* dr = (unsigned short*)(vbf + (size_t)b * K_);
    float acc = 0.f;
    for (int i = t * 8; i < K_; i += 256 * 8) {
        float4 x0 = *(const float4*)(vr + i);
        float4 x1 = *(const float4*)(vr + i + 4);
        float4 b0 = *(const float4*)(bv + i);
        float4 b1 = *(const float4*)(bv + i + 4);
        acc += x0.x*b0.x + x0.y*b0.y + x0.z*b0.z + x0.w*b0.w
             + x1.x*b1.x + x1.y*b1.y + x1.z*b1.z + x1.w*b1.w;
        ushort4 u0, u1;
        u0.x = f2bf(x0.x); u0.y = f2bf(x0.y); u0.z = f2bf(x0.z); u0.w = f2bf(x0.w);
        u1.x = f2bf(x1.x); u1.y = f2bf(x1.y); u1.z = f2bf(x1.z); u1.w = f2bf(x1.w);
        *(ushort4*)(dr + i)     = u0;
        *(ushort4*)(dr + i + 4) = u1;
    }
    __shared__ float sm[256];
    sm[t] = acc;
    __syncthreads();
    for (int s = 128; s > 0; s >>= 1) {
        if (t < s) sm[t] += sm[t + s];
        __syncthreads();
    }
    if (t == 0) vt[b] = sm[0];
}

// ---------------- Kernel B: split-K GEMM, BM=256 BN=64 BK=64 ----------------
// W: global fp32 -> regs (2-ahead) -> cvt bf16 -> ds_write into depth-4 8KB ring,
// with the cvt+write placed MID-COMPUTE (after the barrier, between the two MFMA
// half-bodies) so it hides under MFMAs instead of convoying at the barrier.
// A (v bf16, XCD-L2-resident): direct global->reg, double-buffered.
// Pre-barrier fused wait drains ONLY A(t) (L2 hit) + previous ds_write; W HBM
// latency is absorbed mid-body. vmcnt never 0 in the main loop.
//
// Per-wave vmem FIFO (issue order per body: A(t+1)x4 then Wg(t+2)x2):
//   at pre-barrier of body t: A(t)4, Wg(t+1)2, A(t+1)4, Wg(t+2)2 = 12
//     -> vmcnt(8) drains exactly A(t).
//   mid-body: Wg(t+1)2, A(t+1)4, Wg(t+2)2 = 8 -> vmcnt(6) drains exactly Wg(t+1).
//   Tail: body NT-2 -> pre vmcnt(6), mid vmcnt(4); body NT-1 -> pre vmcnt(0).
// Ring: slot (t+1)&3 written mid-body t, read in body t+1 (after lgkmcnt(0)+bar);
// laggard readers of slot (t+1)&3 = (t-3)&3 finished 2+ barriers earlier. Safe.

#define GLOAD_W(dst, kt) do {                                                          \
    const float* p_ = wsrcp + (size_t)(kt) * 64;                                       \
    dst[0] = *(const float4*)p_;                                                       \
    dst[1] = *(const float4*)(p_ + 4);                                                 \
    } while (0)

#define CVT_WRITE(WG, slot_) do {                                                      \
    bf16x8 u_;                                                                         \
    u_[0]=bfc(WG[0].x); u_[1]=bfc(WG[0].y); u_[2]=bfc(WG[0].z); u_[3]=bfc(WG[0].w);    \
    u_[4]=bfc(WG[1].x); u_[5]=bfc(WG[1].y); u_[6]=bfc(WG[1].z); u_[7]=bfc(WG[1].w);    \
    *(bf16x8*)&wtile[(slot_)][wslot_off] = u_;                                         \
    } while (0)

#define LOAD_A(dst, kt) do {                                                           \
    _Pragma("unroll")                                                                  \
    for (int m_ = 0; m_ < 2; ++m_)                                                     \
      _Pragma("unroll")                                                                \
      for (int s_ = 0; s_ < 2; ++s_)                                                   \
        dst[m_*2+s_] = *(const bf16x8*)(ap[m_] + (size_t)(kt) * 64 + s_ * 32);         \
    } while (0)

// One k-half of a body: 4 swizzled ds_read_b128 B-frags + 8 MFMA.
#define COMPUTE_S(AUSE, T_, S_) do {                                                   \
    const unsigned short* wb_ = &wtile[(T_) & 3][0];                                   \
    bf16x8 bfr[4];                                                                     \
    _Pragma("unroll")                                                                  \
    for (int n_ = 0; n_ < 4; ++n_) {                                                   \
        int row_  = n_ * 16 + lr;                                                      \
        int slot_ = (S_) * 4 + lg;                                                     \
        bfr[n_] = *(const bf16x8*)&wb_[row_ * 64 + ((slot_ ^ (row_ & 7)) << 3)];       \
    }                                                                                  \
    _Pragma("unroll")                                                                  \
    for (int m_ = 0; m_ < 2; ++m_)                                                     \
      _Pragma("unroll")                                                                \
      for (int n_ = 0; n_ < 4; ++n_)                                                   \
        acc[m_][n_] = __builtin_amdgcn_mfma_f32_16x16x32_bf16(                         \
            AUSE[m_*2+(S_)], bfr[n_], acc[m_][n_], 0, 0, 0);                           \
    } while (0)

#define BODY(T_, AUSE, ALOAD, WGUSE, WGLOAD, ISSA, ISSW, DOCVT, VMPRE, VMMID) do {     \
    if (ISSA) LOAD_A(ALOAD, (T_) + 1);                                                 \
    if (ISSW) GLOAD_W(WGLOAD, (T_) + 2);                                               \
    asm volatile("s_waitcnt " VMPRE " lgkmcnt(0)\n\ts_barrier" ::: "memory");          \
    COMPUTE_S(AUSE, T_, 0);                                                            \
    if (DOCVT) {                                                                       \
        asm volatile("s_waitcnt " VMMID ::: "memory");                                 \
        CVT_WRITE(WGUSE, ((T_) + 1) & 3);                                              \
    }                                                                                  \
    COMPUTE_S(AUSE, T_, 1);                                                            \
    } while (0)

__global__ __launch_bounds__(512, 4) void gemm_kernel(
    const __hip_bfloat16* __restrict__ vbf,   // [256][32768] bf16
    const float* __restrict__ W,              // [4096][32768] fp32
    float* __restrict__ part,                 // [KS][256][4096] fp32
    int KS, int NT)                           // NT = (K_/KS)/64, even, >= 4
{
    __shared__ __align__(16) unsigned short wtile[4][64 * 64];  // 4 x 8 KB bf16 ring

    const int tid  = threadIdx.x;
    const int wid  = tid >> 6;
    const int lane = tid & 63;
    const int lr   = lane & 15;   // B-frag n / A-frag row-in-16
    const int lg   = lane >> 4;   // k-granule 0..3

    const int bid   = blockIdx.x;
    const int sidx  = bid % KS;   // k-split; == XCD id when KS==8 (v-slice L2 locality)
    const int ht    = bid / KS;
    const int h0    = ht * 64;
    const int kbase = sidx * (NT * 64);

    // W stage addressing: thread stages row rw = tid>>3, 8 floats at col (tid&7)*8.
    // LDS granule (rw, c8) stored at swizzled slot c8 ^ (rw&7).
    const int rw = tid >> 3;
    const int c8 = tid & 7;
    const float* wsrcp = W + (size_t)(h0 + rw) * K_ + kbase + c8 * 8;
    const int wslot_off = rw * 64 + ((c8 ^ (rw & 7)) << 3);   // ushort index

    // A: this wave owns rows wid*32 .. wid*32+31
    const __hip_bfloat16* ap[2];
    #pragma unroll
    for (int m = 0; m < 2; ++m)
        ap[m] = vbf + (size_t)(wid * 32 + m * 16 + lr) * K_ + kbase + lg * 8;

    f32x4 acc[2][4];
    #pragma unroll
    for (int m = 0; m < 2; ++m)
        #pragma unroll
        for (int n = 0; n < 4; ++n)
            acc[m][n] = (f32x4)(0.0f);

    bf16x8 aA[4], aB[4];
    float4 wgA[2], wgB[2];

    // Prologue: A(0), Wg(0)->wgA, Wg(1)->wgB; drain A(0)+Wg(0) (keep Wg(1));
    // cvt+write slot 0. Body 0's lgkmcnt(0)+barrier makes it visible.
    LOAD_A(aA, 0);
    GLOAD_W(wgA, 0);
    GLOAD_W(wgB, 1);
    asm volatile("s_waitcnt vmcnt(2)" ::: "memory");
    CVT_WRITE(wgA, 0);
    asm volatile("" ::: "memory");

    // even body t: compute aA, cvt wgB=Wg(t+1), load aB=A(t+1), wgA=Wg(t+2); odd: swap.
    for (int t = 0; t < NT - 2; t += 2) {
        BODY(t,     aA, aB, wgB, wgA, true, true, true, "vmcnt(8)", "vmcnt(6)");
        BODY(t + 1, aB, aA, wgA, wgB, true, true, true, "vmcnt(8)", "vmcnt(6)");
    }
    BODY(NT - 2, aA, aB, wgB, wgA, true,  false, true,  "vmcnt(6)", "vmcnt(4)");
    BODY(NT - 1, aB, aA, wgA, wgB, false, false, false, "vmcnt(0)", "vmcnt(0)");

    // Epilogue: C/D layout col=lane&15 (=h), row=(lane>>4)*4+reg (=b)
    float* pout = part + (size_t)sidx * ((size_t)B_ * H_) + h0;
    #pragma unroll
    for (int m = 0; m < 2; ++m)
        #pragma unroll
        for (int n = 0; n < 4; ++n)
            #pragma unroll
            for (int j = 0; j < 4; ++j) {
                int brow = wid * 32 + m * 16 + lg * 4 + j;
                int hcol = n * 16 + lr;
                pout[(size_t)brow * H_ + hcol] = acc[m][n][j];
            }
}

// ---------------- Kernel C: reduce splits + b_h, softplus, sum over H, + vt ----------------
__global__ __launch_bounds__(256) void reduce_kernel(
    const float* __restrict__ part, const float* __restrict__ bh,
    const float* __restrict__ vt, float* __restrict__ out, int KS)
{
    const int b = blockIdx.x;
    const int t = threadIdx.x;
    float sp = 0.f;
    const float* pb = part + (size_t)b * H_;
    for (int h = t * 4; h < H_; h += 256 * 4) {
        float4 l = *(const float4*)(bh + h);
        for (int s = 0; s < KS; ++s) {
            float4 p = *(const float4*)(pb + (size_t)s * B_ * H_ + h);
            l.x += p.x; l.y += p.y; l.z += p.z; l.w += p.w;
        }
        sp += softplus_f(l.x) + softplus_f(l.y) + softplus_f(l.z) + softplus_f(l.w);
    }
    __shared__ float sm[256];
    sm[t] = sp;
    __syncthreads();
    for (int r = 128; r > 0; r >>= 1) {
        if (t < r) sm[t] += sm[t + r];
        __syncthreads();
    }
    if (t == 0) out[b] = sm[0] + vt[b];
}

extern "C" void kernel_launch(void* const* d_in, const int* in_sizes, int n_in,
                              void* d_out, int out_size, void* d_ws, size_t ws_size,
                              hipStream_t stream)
{
    const float* v  = (const float*)d_in[0];
    const float* W  = (const float*)d_in[1];
    const float* bh = (const float*)d_in[2];
    const float* bv = (const float*)d_in[3];
    float* out = (float*)d_out;

    char* ws = (char*)d_ws;
    const size_t vbf_bytes = (size_t)B_ * K_ * sizeof(__hip_bfloat16);  // 16 MB
    __hip_bfloat16* vbf = (__hip_bfloat16*)ws;

    int KS = 8;                                   // shrink if workspace is small
    while (KS > 1 && vbf_bytes + (size_t)KS * B_ * H_ * 4 + 1024 > ws_size) KS >>= 1;

    float* part = (float*)(ws + vbf_bytes);                                  // KS*4 MB
    float* vt   = (float*)(ws + vbf_bytes + (size_t)KS * B_ * H_ * 4);       // 1 KB

    prep_kernel<<<B_, 256, 0, stream>>>(v, bv, vbf, vt);
    const int NT = (K_ / KS) / 64;                // 64 for KS=8 (even, >=4)
    gemm_kernel<<<(H_ / 64) * KS, 512, 0, stream>>>(vbf, W, part, KS, NT);
    reduce_kernel<<<B_, 256, 0, stream>>>(part, bh, vt, out, KS);
}